// Round 1
// baseline (2370.270 us; speedup 1.0000x reference)
//
#include <hip/hip_runtime.h>

// 2-layer GCN, N=1M nodes, E=10M edges, dims 2 -> 8 -> 2.
// Key trick: aggregation is linear, so aggregate the 2-wide features FIRST,
// apply the dense weight AFTER. Both edge passes scatter only 2 floats/edge.
// Self-loops handled analytically in the node-wise kernels.

__global__ void k_deg(const int* __restrict__ dst, int* __restrict__ deg, int ne) {
    int i = blockIdx.x * blockDim.x + threadIdx.x;
    int stride = gridDim.x * blockDim.x;
    for (; i < ne; i += stride) {
        atomicAdd(&deg[dst[i]], 1);
    }
}

__global__ void k_dinv(const int* __restrict__ deg, float* __restrict__ dinv, int nn) {
    int i = blockIdx.x * blockDim.x + threadIdx.x;
    if (i < nn) {
        // +1 for the self-loop; degree always > 0 so no guard needed
        dinv[i] = rsqrtf((float)(deg[i] + 1));
    }
}

// Shared by both layers: scatter-add norm-scaled 2-channel features.
__global__ void k_edge2(const int* __restrict__ src, const int* __restrict__ dst,
                        const float* __restrict__ feat2, const float* __restrict__ dinv,
                        float* __restrict__ agg2, int ne) {
    int i = blockIdx.x * blockDim.x + threadIdx.x;
    int stride = gridDim.x * blockDim.x;
    for (; i < ne; i += stride) {
        int s = src[i];
        int d = dst[i];
        float nrm = dinv[s] * dinv[d];
        float2 f = reinterpret_cast<const float2*>(feat2)[s];
        unsafeAtomicAdd(&agg2[2 * d + 0], nrm * f.x);
        unsafeAtomicAdd(&agg2[2 * d + 1], nrm * f.y);
    }
}

// Node-wise: finish layer-1 aggregation (self-loop), apply W1+b1, ReLU,
// immediately apply W2 -> a2.  h is never materialized.
__global__ void k_mid(const float* __restrict__ x, const float* __restrict__ aggx,
                      const float* __restrict__ dinv,
                      const float* __restrict__ W1, const float* __restrict__ b1,
                      const float* __restrict__ W2,
                      float* __restrict__ a2, int nn) {
    int i = blockIdx.x * blockDim.x + threadIdx.x;
    if (i >= nn) return;
    float di  = dinv[i];
    float di2 = di * di;
    float2 xs = reinterpret_cast<const float2*>(x)[i];
    float ax = aggx[2 * i + 0] + di2 * xs.x;   // self-loop message
    float ay = aggx[2 * i + 1] + di2 * xs.y;
    float o0 = 0.0f, o1 = 0.0f;
#pragma unroll
    for (int k = 0; k < 8; ++k) {
        // W1 is [2,8] row-major, W2 is [8,2] row-major
        float hk = fmaxf(ax * W1[k] + ay * W1[8 + k] + b1[k], 0.0f);
        o0 += hk * W2[2 * k + 0];
        o1 += hk * W2[2 * k + 1];
    }
    a2[2 * i + 0] = o0;
    a2[2 * i + 1] = o1;
}

// Node-wise epilogue for layer 2: self-loop + bias, in place on d_out.
__global__ void k_out(const float* __restrict__ a2, const float* __restrict__ dinv,
                      const float* __restrict__ b2, float* __restrict__ out, int nn) {
    int i = blockIdx.x * blockDim.x + threadIdx.x;
    if (i >= nn) return;
    float di  = dinv[i];
    float di2 = di * di;
    float b0 = b2[0], b1v = b2[1];
    out[2 * i + 0] = out[2 * i + 0] + di2 * a2[2 * i + 0] + b0;
    out[2 * i + 1] = out[2 * i + 1] + di2 * a2[2 * i + 1] + b1v;
}

extern "C" void kernel_launch(void* const* d_in, const int* in_sizes, int n_in,
                              void* d_out, int out_size, void* d_ws, size_t ws_size,
                              hipStream_t stream) {
    const float* x  = (const float*)d_in[0];
    const int*   ei = (const int*)d_in[1];   // [2, E] int32
    const float* W1 = (const float*)d_in[2]; // [2,8]
    const float* b1 = (const float*)d_in[3]; // [8]
    const float* W2 = (const float*)d_in[4]; // [8,2]
    const float* b2 = (const float*)d_in[5]; // [2]
    float* out = (float*)d_out;              // [N,2] fp32

    const int nn = in_sizes[0] / 2;
    const int ne = in_sizes[1] / 2;
    const int* src = ei;
    const int* dst = ei + ne;

    // workspace carve-out (~24 MB)
    char* ws = (char*)d_ws;
    size_t off = 0;
    auto alloc = [&](size_t bytes) -> void* {
        void* p = ws + off;
        off += (bytes + 255) & ~size_t(255);
        return p;
    };
    int*   deg  = (int*)  alloc((size_t)nn * sizeof(int));
    float* dinv = (float*)alloc((size_t)nn * sizeof(float));
    float* aggx = (float*)alloc((size_t)nn * 2 * sizeof(float));
    float* a2   = (float*)alloc((size_t)nn * 2 * sizeof(float));

    hipMemsetAsync(deg,  0, (size_t)nn * sizeof(int), stream);
    hipMemsetAsync(aggx, 0, (size_t)nn * 2 * sizeof(float), stream);
    hipMemsetAsync(d_out, 0, (size_t)nn * 2 * sizeof(float), stream);

    const int TB = 256;
    int egrid = (ne + TB - 1) / TB;
    int ngrid = (nn + TB - 1) / TB;

    k_deg  <<<egrid, TB, 0, stream>>>(dst, deg, ne);
    k_dinv <<<ngrid, TB, 0, stream>>>(deg, dinv, nn);
    k_edge2<<<egrid, TB, 0, stream>>>(src, dst, x,  dinv, aggx, ne);
    k_mid  <<<ngrid, TB, 0, stream>>>(x, aggx, dinv, W1, b1, W2, a2, nn);
    k_edge2<<<egrid, TB, 0, stream>>>(src, dst, a2, dinv, out, ne);
    k_out  <<<ngrid, TB, 0, stream>>>(a2, dinv, b2, out, nn);
}

// Round 2
// 420.968 us; speedup vs baseline: 5.6305x; 5.6305x over previous
//
#include <hip/hip_runtime.h>

// 2-layer GCN, N=1M (< 2^20) nodes, E=10M edges, dims 2 -> 8 -> 2.
//
// Strategy: counting-sort edges by dst into NB=1024 buckets of 1024 nodes,
// then one workgroup per bucket accumulates messages in LDS (no global float
// atomics, no cross-XCD cache-line bouncing). Features are pre-scaled by
// dinv[src] node-wise and post-scaled by dinv[dst] in the epilogue, so the
// edge loop gathers a single float2. Sorted edges pack (src<<10)|(dst&1023)
// in 32 bits. Self-loops handled analytically.

#define NB    1024
#define SHIFT 10
#define WMASK 1023
#define EPW   16384  // edges per scatter workgroup (256 thr x 64)

// ---------- sort pipeline ----------

__global__ void s_hist(const int* __restrict__ dst, int* __restrict__ ghist, int ne) {
    __shared__ int h[NB];
    for (int i = threadIdx.x; i < NB; i += blockDim.x) h[i] = 0;
    __syncthreads();
    int i = blockIdx.x * blockDim.x + threadIdx.x;
    int stride = gridDim.x * blockDim.x;
    for (; i < ne; i += stride) atomicAdd(&h[dst[i] >> SHIFT], 1);
    __syncthreads();
    for (int b = threadIdx.x; b < NB; b += blockDim.x)
        if (h[b]) atomicAdd(&ghist[b], h[b]);
}

__global__ void s_scan(const int* __restrict__ ghist, int* __restrict__ start,
                       int* __restrict__ tail) {
    __shared__ int buf[NB];
    int t = threadIdx.x;           // launched with 1024 threads
    int own = ghist[t];
    buf[t] = own;
    __syncthreads();
    for (int off = 1; off < NB; off <<= 1) {
        int add = (t >= off) ? buf[t - off] : 0;
        __syncthreads();
        buf[t] += add;
        __syncthreads();
    }
    int excl = buf[t] - own;       // exclusive prefix
    start[t] = excl;
    tail[t]  = excl;
    if (t == NB - 1) start[NB] = buf[NB - 1];
}

__global__ void s_scatter(const int* __restrict__ src, const int* __restrict__ dst,
                          int ne, int* __restrict__ tail, unsigned* __restrict__ sorted) {
    __shared__ int h[NB];
    __shared__ int wbase[NB];
    __shared__ int run[NB];
    int c0 = blockIdx.x * EPW;
    int c1 = min(c0 + EPW, ne);
    for (int i = threadIdx.x; i < NB; i += blockDim.x) { h[i] = 0; run[i] = 0; }
    __syncthreads();
    for (int e = c0 + threadIdx.x; e < c1; e += blockDim.x)
        atomicAdd(&h[dst[e] >> SHIFT], 1);
    __syncthreads();
    for (int b = threadIdx.x; b < NB; b += blockDim.x)
        if (h[b]) wbase[b] = atomicAdd(&tail[b], h[b]);
    __syncthreads();
    for (int e = c0 + threadIdx.x; e < c1; e += blockDim.x) {
        int d = dst[e];
        int b = d >> SHIFT;
        int off = atomicAdd(&run[b], 1);
        sorted[wbase[b] + off] = ((unsigned)src[e] << SHIFT) | (unsigned)(d & WMASK);
    }
}

// Per-bucket: count in-degree in LDS, emit dinv and pre-scaled features xs.
__global__ void s_deg(const unsigned* __restrict__ sorted, const int* __restrict__ start,
                      const float2* __restrict__ x, float* __restrict__ dinv,
                      float2* __restrict__ xs, int nn) {
    __shared__ int cnt[NB];
    int b = blockIdx.x;
    for (int i = threadIdx.x; i < NB; i += blockDim.x) cnt[i] = 0;
    __syncthreads();
    int e0 = start[b], e1 = start[b + 1];
    for (int e = e0 + threadIdx.x; e < e1; e += blockDim.x)
        atomicAdd(&cnt[sorted[e] & WMASK], 1);
    __syncthreads();
    int base = b << SHIFT;
    for (int j = threadIdx.x; j < NB; j += blockDim.x) {
        int node = base + j;
        if (node < nn) {
            float di = rsqrtf((float)(cnt[j] + 1));   // +1 self-loop
            dinv[node] = di;
            float2 xv = x[node];
            xs[node] = make_float2(xv.x * di, xv.y * di);
        }
    }
}

// Per-bucket aggregation + fused node-wise epilogue.
// LAYER==1: A1 = dinv*(sum xs[s]) + dinv^2*x ; h=relu(W1^T A1+b1); a2=W2^T h;
//           writes a2 and xs2 = a2*dinv.
// LAYER==2: out = dinv*(sum xs2[s]) + dinv^2*a2 + b2.
template <int LAYER>
__global__ void s_agg(const unsigned* __restrict__ sorted, const int* __restrict__ start,
                      const float2* __restrict__ feat, const float* __restrict__ dinv,
                      const float2* __restrict__ sv_arr,
                      const float* __restrict__ W1, const float* __restrict__ b1,
                      const float* __restrict__ W2, const float* __restrict__ b2,
                      float2* __restrict__ out_a2, float2* __restrict__ out_xs2,
                      float2* __restrict__ out_final, int nn) {
    __shared__ float accx[NB];
    __shared__ float accy[NB];
    int b = blockIdx.x;
    for (int i = threadIdx.x; i < NB; i += blockDim.x) { accx[i] = 0.f; accy[i] = 0.f; }
    __syncthreads();
    int e0 = start[b], e1 = start[b + 1];
    for (int e = e0 + threadIdx.x; e < e1; e += blockDim.x) {
        unsigned v = sorted[e];
        float2 f = feat[v >> SHIFT];     // gather pre-scaled source feature
        int j = v & WMASK;
        atomicAdd(&accx[j], f.x);
        atomicAdd(&accy[j], f.y);
    }
    __syncthreads();
    int base = b << SHIFT;
    for (int j = threadIdx.x; j < NB; j += blockDim.x) {
        int node = base + j;
        if (node >= nn) continue;
        float di = dinv[node];
        float2 sv = sv_arr[node];        // x (L1) or a2 (L2) for the self-loop term
        float ax = di * accx[j] + di * di * sv.x;
        float ay = di * accy[j] + di * di * sv.y;
        if (LAYER == 1) {
            float o0 = 0.f, o1 = 0.f;
#pragma unroll
            for (int k = 0; k < 8; ++k) {
                float hk = fmaxf(ax * W1[k] + ay * W1[8 + k] + b1[k], 0.f);
                o0 += hk * W2[2 * k + 0];
                o1 += hk * W2[2 * k + 1];
            }
            out_a2[node]  = make_float2(o0, o1);
            out_xs2[node] = make_float2(o0 * di, o1 * di);
        } else {
            out_final[node] = make_float2(ax + b2[0], ay + b2[1]);
        }
    }
}

// ---------- fallback (round-1 algorithm, needs only ~24 MB scratch) ----------

__global__ void k_deg(const int* __restrict__ dst, int* __restrict__ deg, int ne) {
    int i = blockIdx.x * blockDim.x + threadIdx.x;
    int stride = gridDim.x * blockDim.x;
    for (; i < ne; i += stride) atomicAdd(&deg[dst[i]], 1);
}
__global__ void k_dinv(const int* __restrict__ deg, float* __restrict__ dinv, int nn) {
    int i = blockIdx.x * blockDim.x + threadIdx.x;
    if (i < nn) dinv[i] = rsqrtf((float)(deg[i] + 1));
}
__global__ void k_edge2(const int* __restrict__ src, const int* __restrict__ dst,
                        const float* __restrict__ feat2, const float* __restrict__ dinv,
                        float* __restrict__ agg2, int ne) {
    int i = blockIdx.x * blockDim.x + threadIdx.x;
    int stride = gridDim.x * blockDim.x;
    for (; i < ne; i += stride) {
        int s = src[i], d = dst[i];
        float nrm = dinv[s] * dinv[d];
        float2 f = reinterpret_cast<const float2*>(feat2)[s];
        unsafeAtomicAdd(&agg2[2 * d + 0], nrm * f.x);
        unsafeAtomicAdd(&agg2[2 * d + 1], nrm * f.y);
    }
}
__global__ void k_mid(const float* __restrict__ x, const float* __restrict__ aggx,
                      const float* __restrict__ dinv,
                      const float* __restrict__ W1, const float* __restrict__ b1,
                      const float* __restrict__ W2, float* __restrict__ a2, int nn) {
    int i = blockIdx.x * blockDim.x + threadIdx.x;
    if (i >= nn) return;
    float di = dinv[i], di2 = di * di;
    float2 xs = reinterpret_cast<const float2*>(x)[i];
    float ax = aggx[2 * i + 0] + di2 * xs.x;
    float ay = aggx[2 * i + 1] + di2 * xs.y;
    float o0 = 0.f, o1 = 0.f;
#pragma unroll
    for (int k = 0; k < 8; ++k) {
        float hk = fmaxf(ax * W1[k] + ay * W1[8 + k] + b1[k], 0.f);
        o0 += hk * W2[2 * k + 0];
        o1 += hk * W2[2 * k + 1];
    }
    a2[2 * i + 0] = o0;
    a2[2 * i + 1] = o1;
}
__global__ void k_out(const float* __restrict__ a2, const float* __restrict__ dinv,
                      const float* __restrict__ b2, float* __restrict__ out, int nn) {
    int i = blockIdx.x * blockDim.x + threadIdx.x;
    if (i >= nn) return;
    float di = dinv[i], di2 = di * di;
    out[2 * i + 0] = out[2 * i + 0] + di2 * a2[2 * i + 0] + b2[0];
    out[2 * i + 1] = out[2 * i + 1] + di2 * a2[2 * i + 1] + b2[1];
}

extern "C" void kernel_launch(void* const* d_in, const int* in_sizes, int n_in,
                              void* d_out, int out_size, void* d_ws, size_t ws_size,
                              hipStream_t stream) {
    const float* x  = (const float*)d_in[0];
    const int*   ei = (const int*)d_in[1];
    const float* W1 = (const float*)d_in[2];
    const float* b1 = (const float*)d_in[3];
    const float* W2 = (const float*)d_in[4];
    const float* b2 = (const float*)d_in[5];
    float* out = (float*)d_out;

    const int nn = in_sizes[0] / 2;
    const int ne = in_sizes[1] / 2;
    const int* src = ei;
    const int* dst = ei + ne;

    char* ws = (char*)d_ws;
    size_t off = 0;
    auto alloc = [&](size_t bytes) -> void* {
        void* p = ws + off;
        off += (bytes + 255) & ~size_t(255);
        return p;
    };

    size_t need = (size_t)ne * 4 + (size_t)nn * 4 + 3 * (size_t)nn * 8 + (3 * NB + 16) * 4 + 4096;

    const int TB = 256;
    if (ws_size >= need) {
        unsigned* sorted = (unsigned*)alloc((size_t)ne * 4);
        float*    dinv   = (float*)   alloc((size_t)nn * 4);
        float2*   xs     = (float2*)  alloc((size_t)nn * 8);
        float2*   a2     = (float2*)  alloc((size_t)nn * 8);
        float2*   xs2    = (float2*)  alloc((size_t)nn * 8);
        int*      ghist  = (int*)     alloc(NB * 4);
        int*      start  = (int*)     alloc((NB + 1) * 4);
        int*      tail   = (int*)     alloc(NB * 4);

        hipMemsetAsync(ghist, 0, NB * 4, stream);

        int sgrid = (ne + EPW - 1) / EPW;
        s_hist   <<<1024, TB, 0, stream>>>(dst, ghist, ne);
        s_scan   <<<1, NB, 0, stream>>>(ghist, start, tail);
        s_scatter<<<sgrid, TB, 0, stream>>>(src, dst, ne, tail, sorted);
        s_deg    <<<NB, TB, 0, stream>>>(sorted, start, (const float2*)x, dinv, xs, nn);
        s_agg<1> <<<NB, TB, 0, stream>>>(sorted, start, xs, dinv, (const float2*)x,
                                         W1, b1, W2, b2, a2, xs2, nullptr, nn);
        s_agg<2> <<<NB, TB, 0, stream>>>(sorted, start, xs2, dinv, a2,
                                         W1, b1, W2, b2, nullptr, nullptr,
                                         (float2*)out, nn);
    } else {
        // fallback: round-1 algorithm (~24 MB scratch)
        int*   deg  = (int*)  alloc((size_t)nn * 4);
        float* dinv = (float*)alloc((size_t)nn * 4);
        float* aggx = (float*)alloc((size_t)nn * 8);
        float* a2   = (float*)alloc((size_t)nn * 8);
        hipMemsetAsync(deg,  0, (size_t)nn * 4, stream);
        hipMemsetAsync(aggx, 0, (size_t)nn * 8, stream);
        hipMemsetAsync(d_out, 0, (size_t)nn * 8, stream);
        int egrid = (ne + TB - 1) / TB;
        int ngrid = (nn + TB - 1) / TB;
        k_deg  <<<egrid, TB, 0, stream>>>(dst, deg, ne);
        k_dinv <<<ngrid, TB, 0, stream>>>(deg, dinv, nn);
        k_edge2<<<egrid, TB, 0, stream>>>(src, dst, x, dinv, aggx, ne);
        k_mid  <<<ngrid, TB, 0, stream>>>(x, aggx, dinv, W1, b1, W2, a2, nn);
        k_edge2<<<egrid, TB, 0, stream>>>(src, dst, a2, dinv, out, ne);
        k_out  <<<ngrid, TB, 0, stream>>>(a2, dinv, b2, out, nn);
    }
}

// Round 3
// 360.162 us; speedup vs baseline: 6.5811x; 1.1688x over previous
//
#include <hip/hip_runtime.h>

// 2-layer GCN, N=1M (< 2^20) nodes, E=10M edges, dims 2 -> 8 -> 2.
//
// Deterministic line-aligned counting sort by dst into NB=1024 buckets of
// 1024 nodes, then one WG per bucket accumulates messages in LDS (no global
// float atomics). Each (chunk,bucket) sub-range is padded to 16 edges (64B)
// so every scatter write run is line-aligned and private -> no cross-XCD
// partial-line RMW. Pad slots hold a sentinel that contributes nothing.
// Features are pre-scaled by dinv[src] so the edge loop gathers one float2;
// the self-loop term is dinv*(pre-scaled self feature), folded into the
// same accumulator.

#define NB    1024
#define SHIFT 10
#define WMASK 1023u
#define EPW   65536          // edges per chunk
#define IDXMASK 0x1FFFFFu    // 21-bit source index (sentinel maps to nn)

// ---------- sort pipeline ----------

// Per-chunk histogram, rounded up to 16-edge (64B) capacity.
__global__ void h_hist(const int* __restrict__ dst, int ne, int* __restrict__ ghist) {
    __shared__ int h[NB];
    int c = blockIdx.x;
    int c0 = c * EPW, c1 = min(c0 + EPW, ne);
    for (int b = threadIdx.x; b < NB; b += blockDim.x) h[b] = 0;
    __syncthreads();
    int n4 = (c1 - c0) >> 2;
    const int4* d4 = (const int4*)(dst + c0);
    for (int g = threadIdx.x; g < n4; g += blockDim.x) {
        int4 d = d4[g];
        atomicAdd(&h[d.x >> SHIFT], 1);
        atomicAdd(&h[d.y >> SHIFT], 1);
        atomicAdd(&h[d.z >> SHIFT], 1);
        atomicAdd(&h[d.w >> SHIFT], 1);
    }
    for (int e = c0 + (n4 << 2) + threadIdx.x; e < c1; e += blockDim.x)
        atomicAdd(&h[dst[e] >> SHIFT], 1);
    __syncthreads();
    for (int b = threadIdx.x; b < NB; b += blockDim.x)
        ghist[c * NB + b] = (h[b] + 15) & ~15;     // 64B-aligned capacity
}

// Exclusive scan of each bucket's capacity column across chunks.
__global__ void h_colscan(int* __restrict__ ghist, int* __restrict__ tot, int nc) {
    __shared__ int buf[256];   // nc <= 256
    int b = blockIdx.x;
    for (int c = threadIdx.x; c < nc; c += blockDim.x) buf[c] = ghist[c * NB + b];
    __syncthreads();
    if (threadIdx.x == 0) {
        int s = 0;
        for (int c = 0; c < nc; ++c) { int v = buf[c]; buf[c] = s; s += v; }
        tot[b] = s;
    }
    __syncthreads();
    for (int c = threadIdx.x; c < nc; c += blockDim.x) ghist[c * NB + b] = buf[c];
}

// Exclusive scan of bucket totals -> bucket starts (all multiples of 16).
__global__ void s_scan(const int* __restrict__ tot, int* __restrict__ start) {
    __shared__ int buf[NB];
    int t = threadIdx.x;               // 1024 threads
    int own = tot[t];
    buf[t] = own;
    __syncthreads();
    for (int off = 1; off < NB; off <<= 1) {
        int add = (t >= off) ? buf[t - off] : 0;
        __syncthreads();
        buf[t] += add;
        __syncthreads();
    }
    start[t] = buf[t] - own;
    if (t == NB - 1) start[NB] = buf[NB - 1];
}

// Deterministic scatter into private, aligned sub-ranges + sentinel fill.
__global__ void h_scatter(const int* __restrict__ src, const int* __restrict__ dst,
                          int ne, const int* __restrict__ colx,
                          const int* __restrict__ start,
                          unsigned* __restrict__ sorted, unsigned sent) {
    __shared__ int wb[NB];
    __shared__ int run[NB];
    int c = blockIdx.x;
    int c0 = c * EPW, c1 = min(c0 + EPW, ne);
    for (int b = threadIdx.x; b < NB; b += blockDim.x) {
        wb[b] = start[b] + colx[c * NB + b];
        run[b] = 0;
    }
    __syncthreads();
    int n4 = (c1 - c0) >> 2;
    const int4* s4 = (const int4*)(src + c0);
    const int4* d4 = (const int4*)(dst + c0);
    for (int g = threadIdx.x; g < n4; g += blockDim.x) {
        int4 s = s4[g];
        int4 d = d4[g];
        {
            int b = d.x >> SHIFT; int off = atomicAdd(&run[b], 1);
            sorted[wb[b] + off] = ((unsigned)s.x << SHIFT) | ((unsigned)d.x & WMASK);
        }
        {
            int b = d.y >> SHIFT; int off = atomicAdd(&run[b], 1);
            sorted[wb[b] + off] = ((unsigned)s.y << SHIFT) | ((unsigned)d.y & WMASK);
        }
        {
            int b = d.z >> SHIFT; int off = atomicAdd(&run[b], 1);
            sorted[wb[b] + off] = ((unsigned)s.z << SHIFT) | ((unsigned)d.z & WMASK);
        }
        {
            int b = d.w >> SHIFT; int off = atomicAdd(&run[b], 1);
            sorted[wb[b] + off] = ((unsigned)s.w << SHIFT) | ((unsigned)d.w & WMASK);
        }
    }
    for (int e = c0 + (n4 << 2) + threadIdx.x; e < c1; e += blockDim.x) {
        int d = dst[e];
        int b = d >> SHIFT; int off = atomicAdd(&run[b], 1);
        sorted[wb[b] + off] = ((unsigned)src[e] << SHIFT) | ((unsigned)d & WMASK);
    }
    __syncthreads();
    for (int b = threadIdx.x; b < NB; b += blockDim.x) {
        int cnt = run[b];
        int cap = (cnt + 15) & ~15;
        int base = wb[b];
        for (int k = cnt; k < cap; ++k) sorted[base + k] = sent;
    }
}

// Per-bucket in-degree (skip sentinels via bit 31) -> dinv, pre-scaled xs.
__global__ void s_deg(const unsigned* __restrict__ sorted, const int* __restrict__ start,
                      const float2* __restrict__ x, float* __restrict__ dinv,
                      float2* __restrict__ xs, int nn) {
    __shared__ int cnt[NB];
    int b = blockIdx.x;
    for (int i = threadIdx.x; i < NB; i += blockDim.x) cnt[i] = 0;
    __syncthreads();
    int e0 = start[b], e1 = start[b + 1];
    int n4 = (e1 - e0) >> 2;
    const uint4* sv = (const uint4*)(sorted + e0);
    for (int g = threadIdx.x; g < n4; g += blockDim.x) {
        uint4 v = sv[g];
        if (!(v.x >> 31)) atomicAdd(&cnt[v.x & WMASK], 1);
        if (!(v.y >> 31)) atomicAdd(&cnt[v.y & WMASK], 1);
        if (!(v.z >> 31)) atomicAdd(&cnt[v.z & WMASK], 1);
        if (!(v.w >> 31)) atomicAdd(&cnt[v.w & WMASK], 1);
    }
    __syncthreads();
    int base = b << SHIFT;
    for (int j = threadIdx.x; j < NB; j += blockDim.x) {
        int node = base + j;
        if (node < nn) {
            float di = rsqrtf((float)(cnt[j] + 1));   // +1 self-loop
            dinv[node] = di;
            float2 xv = x[node];
            xs[node] = make_float2(xv.x * di, xv.y * di);
        }
    }
    if (b == 0 && threadIdx.x == 0) xs[nn] = make_float2(0.f, 0.f);
}

// Per-bucket aggregation + fused epilogue.
// LAYER==1: A = di*(acc + feat[node]); h=relu(W1^T A+b1); write xs2 = (W2^T h)*di
// LAYER==2: out = di*(acc + feat[node]) + b2
template <int LAYER>
__global__ void s_agg(const unsigned* __restrict__ sorted, const int* __restrict__ start,
                      const float2* __restrict__ feat, const float* __restrict__ dinv,
                      const float* __restrict__ W1, const float* __restrict__ b1,
                      const float* __restrict__ W2, const float* __restrict__ b2,
                      float2* __restrict__ outv, int nn) {
    __shared__ float accx[NB];
    __shared__ float accy[NB];
    int b = blockIdx.x;
    for (int i = threadIdx.x; i < NB; i += blockDim.x) { accx[i] = 0.f; accy[i] = 0.f; }
    __syncthreads();
    int e0 = start[b], e1 = start[b + 1];
    int n4 = (e1 - e0) >> 2;
    const uint4* sv = (const uint4*)(sorted + e0);
    for (int g = threadIdx.x; g < n4; g += blockDim.x) {
        uint4 v = sv[g];
        {
            float2 f = feat[(v.x >> SHIFT) & IDXMASK]; int j = v.x & WMASK;
            atomicAdd(&accx[j], f.x); atomicAdd(&accy[j], f.y);
        }
        {
            float2 f = feat[(v.y >> SHIFT) & IDXMASK]; int j = v.y & WMASK;
            atomicAdd(&accx[j], f.x); atomicAdd(&accy[j], f.y);
        }
        {
            float2 f = feat[(v.z >> SHIFT) & IDXMASK]; int j = v.z & WMASK;
            atomicAdd(&accx[j], f.x); atomicAdd(&accy[j], f.y);
        }
        {
            float2 f = feat[(v.w >> SHIFT) & IDXMASK]; int j = v.w & WMASK;
            atomicAdd(&accx[j], f.x); atomicAdd(&accy[j], f.y);
        }
    }
    __syncthreads();
    int base = b << SHIFT;
    for (int j = threadIdx.x; j < NB; j += blockDim.x) {
        int node = base + j;
        if (node >= nn) continue;
        float di = dinv[node];
        float2 self = feat[node];
        float ax = di * (accx[j] + self.x);
        float ay = di * (accy[j] + self.y);
        if (LAYER == 1) {
            float o0 = 0.f, o1 = 0.f;
#pragma unroll
            for (int k = 0; k < 8; ++k) {
                float hk = fmaxf(ax * W1[k] + ay * W1[8 + k] + b1[k], 0.f);
                o0 += hk * W2[2 * k + 0];
                o1 += hk * W2[2 * k + 1];
            }
            outv[node] = make_float2(o0 * di, o1 * di);   // pre-scaled for layer 2
        } else {
            outv[node] = make_float2(ax + b2[0], ay + b2[1]);
        }
    }
    if (LAYER == 1 && b == 0 && threadIdx.x == 0) outv[nn] = make_float2(0.f, 0.f);
}

// ---------- fallback (round-1 algorithm, ~24 MB scratch) ----------

__global__ void k_deg(const int* __restrict__ dst, int* __restrict__ deg, int ne) {
    int i = blockIdx.x * blockDim.x + threadIdx.x;
    int stride = gridDim.x * blockDim.x;
    for (; i < ne; i += stride) atomicAdd(&deg[dst[i]], 1);
}
__global__ void k_dinv(const int* __restrict__ deg, float* __restrict__ dinv, int nn) {
    int i = blockIdx.x * blockDim.x + threadIdx.x;
    if (i < nn) dinv[i] = rsqrtf((float)(deg[i] + 1));
}
__global__ void k_edge2(const int* __restrict__ src, const int* __restrict__ dst,
                        const float* __restrict__ feat2, const float* __restrict__ dinv,
                        float* __restrict__ agg2, int ne) {
    int i = blockIdx.x * blockDim.x + threadIdx.x;
    int stride = gridDim.x * blockDim.x;
    for (; i < ne; i += stride) {
        int s = src[i], d = dst[i];
        float nrm = dinv[s] * dinv[d];
        float2 f = reinterpret_cast<const float2*>(feat2)[s];
        unsafeAtomicAdd(&agg2[2 * d + 0], nrm * f.x);
        unsafeAtomicAdd(&agg2[2 * d + 1], nrm * f.y);
    }
}
__global__ void k_mid(const float* __restrict__ x, const float* __restrict__ aggx,
                      const float* __restrict__ dinv,
                      const float* __restrict__ W1, const float* __restrict__ b1,
                      const float* __restrict__ W2, float* __restrict__ a2, int nn) {
    int i = blockIdx.x * blockDim.x + threadIdx.x;
    if (i >= nn) return;
    float di = dinv[i], di2 = di * di;
    float2 xsv = reinterpret_cast<const float2*>(x)[i];
    float ax = aggx[2 * i + 0] + di2 * xsv.x;
    float ay = aggx[2 * i + 1] + di2 * xsv.y;
    float o0 = 0.f, o1 = 0.f;
#pragma unroll
    for (int k = 0; k < 8; ++k) {
        float hk = fmaxf(ax * W1[k] + ay * W1[8 + k] + b1[k], 0.f);
        o0 += hk * W2[2 * k + 0];
        o1 += hk * W2[2 * k + 1];
    }
    a2[2 * i + 0] = o0;
    a2[2 * i + 1] = o1;
}
__global__ void k_out(const float* __restrict__ a2, const float* __restrict__ dinv,
                      const float* __restrict__ b2, float* __restrict__ out, int nn) {
    int i = blockIdx.x * blockDim.x + threadIdx.x;
    if (i >= nn) return;
    float di = dinv[i], di2 = di * di;
    out[2 * i + 0] = out[2 * i + 0] + di2 * a2[2 * i + 0] + b2[0];
    out[2 * i + 1] = out[2 * i + 1] + di2 * a2[2 * i + 1] + b2[1];
}

extern "C" void kernel_launch(void* const* d_in, const int* in_sizes, int n_in,
                              void* d_out, int out_size, void* d_ws, size_t ws_size,
                              hipStream_t stream) {
    const float* x  = (const float*)d_in[0];
    const int*   ei = (const int*)d_in[1];
    const float* W1 = (const float*)d_in[2];
    const float* b1 = (const float*)d_in[3];
    const float* W2 = (const float*)d_in[4];
    const float* b2 = (const float*)d_in[5];
    float* out = (float*)d_out;

    const int nn = in_sizes[0] / 2;
    const int ne = in_sizes[1] / 2;
    const int* src = ei;
    const int* dst = ei + ne;

    char* ws = (char*)d_ws;
    size_t off = 0;
    auto alloc = [&](size_t bytes) -> void* {
        void* p = ws + off;
        off += (bytes + 255) & ~size_t(255);
        return p;
    };

    const int nc = (ne + EPW - 1) / EPW;   // chunks
    // worst-case sorted size: ne + per-(chunk,bucket) pad of up to 15
    size_t sorted_elems = (size_t)ne + (size_t)nc * NB * 16;
    size_t need = sorted_elems * 4 + (size_t)nn * 4 + 2 * ((size_t)nn + 1) * 8
                + (size_t)nc * NB * 4 + (NB + 1 + NB) * 4 + 8192;

    const int TB = 256;
    if (ws_size >= need && nc <= 256) {
        unsigned* sorted = (unsigned*)alloc(sorted_elems * 4);
        float*    dinv   = (float*)   alloc((size_t)nn * 4);
        float2*   xs     = (float2*)  alloc(((size_t)nn + 1) * 8);
        float2*   xs2    = (float2*)  alloc(((size_t)nn + 1) * 8);
        int*      ghist  = (int*)     alloc((size_t)nc * NB * 4);
        int*      tot    = (int*)     alloc(NB * 4);
        int*      start  = (int*)     alloc((NB + 1) * 4);

        unsigned sent = 0x80000000u | ((unsigned)nn << SHIFT);

        h_hist   <<<nc, 1024, 0, stream>>>(dst, ne, ghist);
        h_colscan<<<NB, 64, 0, stream>>>(ghist, tot, nc);
        s_scan   <<<1, NB, 0, stream>>>(tot, start);
        h_scatter<<<nc, 1024, 0, stream>>>(src, dst, ne, ghist, start, sorted, sent);
        s_deg    <<<NB, TB, 0, stream>>>(sorted, start, (const float2*)x, dinv, xs, nn);
        s_agg<1> <<<NB, TB, 0, stream>>>(sorted, start, xs, dinv, W1, b1, W2, b2, xs2, nn);
        s_agg<2> <<<NB, TB, 0, stream>>>(sorted, start, xs2, dinv, W1, b1, W2, b2,
                                         (float2*)out, nn);
    } else {
        // fallback: round-1 algorithm
        int*   deg  = (int*)  alloc((size_t)nn * 4);
        float* dinv = (float*)alloc((size_t)nn * 4);
        float* aggx = (float*)alloc((size_t)nn * 8);
        float* a2   = (float*)alloc((size_t)nn * 8);
        hipMemsetAsync(deg,  0, (size_t)nn * 4, stream);
        hipMemsetAsync(aggx, 0, (size_t)nn * 8, stream);
        hipMemsetAsync(d_out, 0, (size_t)nn * 8, stream);
        int egrid = (ne + TB - 1) / TB;
        int ngrid = (nn + TB - 1) / TB;
        k_deg  <<<egrid, TB, 0, stream>>>(dst, deg, ne);
        k_dinv <<<ngrid, TB, 0, stream>>>(deg, dinv, nn);
        k_edge2<<<egrid, TB, 0, stream>>>(src, dst, x, dinv, aggx, ne);
        k_mid  <<<ngrid, TB, 0, stream>>>(x, aggx, dinv, W1, b1, W2, a2, nn);
        k_edge2<<<egrid, TB, 0, stream>>>(src, dst, a2, dinv, out, ne);
        k_out  <<<ngrid, TB, 0, stream>>>(a2, dinv, b2, out, nn);
    }
}